// Round 3
// baseline (201.651 us; speedup 1.0000x reference)
//
#include <hip/hip_runtime.h>
#include <hip/hip_bf16.h>
#include <math.h>

#define RR 1024
#define BB 16
#define DD 1024
#define K_ACTIVE 20

// ---------------------------------------------------------------------------
// Kernel 1: per (r,b) pair compute dot(H[r,b,:], w) and sumsq(msg[r,b,:]),
// then adj[b,r] = s - theta[r] - refr[b,r] - 0.5*(0.9*fb[b,r] + 0.1*||msg||).
// ALSO zero-fills Hs[pair,:] (the 98%-zeros output) while streaming, so the
// 64 MB zero write does not sit behind the NMS dependency. One wave per pair.
// Carries ~all mandatory HBM traffic (128 MB read + 64 MB write).
// ---------------------------------------------------------------------------
__global__ __launch_bounds__(256) void score_kernel(
    const float* __restrict__ H, const float* __restrict__ msg,
    const float* __restrict__ w, const float* __restrict__ theta,
    const float* __restrict__ refr, const float* __restrict__ fb,
    float* __restrict__ adj_out, float* __restrict__ Hs)
{
    const int wave = threadIdx.x >> 6;
    const int lane = threadIdx.x & 63;
    const int pair = blockIdx.x * 4 + wave;   // pair = r*BB + b (row-major [R,B])
    const int r = pair >> 4;
    const int b = pair & 15;

    const float4* H4 = (const float4*)(H + (size_t)pair * DD);
    const float4* M4 = (const float4*)(msg + (size_t)pair * DD);
    const float4* W4 = (const float4*)w;
    float4* Z4 = (float4*)(Hs + (size_t)pair * DD);

    const float4 zero4 = make_float4(0.f, 0.f, 0.f, 0.f);
    float dot = 0.f, ss = 0.f;
#pragma unroll
    for (int k = 0; k < 4; ++k) {
        const int i = lane + 64 * k;          // 256 float4 = 1024 floats
        const float4 h = H4[i];
        const float4 m = M4[i];
        const float4 ww = W4[i];
        Z4[i] = zero4;                        // zero-fill Hs (selected rows
                                              // overwritten by nms_gate)
        dot += h.x * ww.x + h.y * ww.y + h.z * ww.z + h.w * ww.w;
        ss  += m.x * m.x + m.y * m.y + m.z * m.z + m.w * m.w;
    }
    // wave-64 reduction
#pragma unroll
    for (int off = 32; off > 0; off >>= 1) {
        dot += __shfl_down(dot, off);
        ss  += __shfl_down(ss, off);
    }
    if (lane == 0) {
        const float fb_mag = sqrtf(ss);
        const float fb_new = 0.9f * fb[b * RR + r] + 0.1f * fb_mag;
        const float a = dot - theta[r] - refr[b * RR + r] - 0.5f * fb_new;
        adj_out[b * RR + r] = a;
    }
}

// ---------------------------------------------------------------------------
// Kernel 2 (fused NMS + gate): one block per batch, 256 threads.
//   Wave 0: greedy hex NMS, fully register-resident (identical logic to the
//     previous standalone nms_kernel — depth-4 register argmax tree with
//     tie -> lower index, 6-step shfl_xor butterfly, bitmask suppression,
//     neighbors from an LDS copy of nbrs). Writes hard[b,:] and deposits
//     the selected region list + count into LDS.
//   Then all 4 waves copy the <=20 selected rows H[r,b,:] -> Hs[r,b,:]
//     (zeros were pre-written by score_kernel). Wave-per-slot, 4 unrolled
//     float4 chunks per row so each row's loads pipeline.
// Removes: one kernel launch, the hard-matrix re-read, the 16384-pair scan.
// ---------------------------------------------------------------------------
__global__ __launch_bounds__(256) void nms_gate_kernel(
    const float* __restrict__ adj, const int* __restrict__ nbrs,
    const float* __restrict__ H,
    float* __restrict__ hard, float* __restrict__ Hs)
{
    __shared__ int nb_lds[RR * 6];            // 24 KiB
    __shared__ int sel_r[K_ACTIVE];
    __shared__ int nsel_lds;

    const int b = blockIdx.x;
    const int tid = threadIdx.x;
    const int lane = tid & 63;
    const int wave = tid >> 6;

    // Preload neighbor table: 6144 ints = 1536 int4, 6 int4 per thread.
    {
        const int4* nb4 = (const int4*)nbrs;
        int4* nl4 = (int4*)nb_lds;
#pragma unroll
        for (int j = 0; j < 6; ++j)
            nl4[tid + 256 * j] = nb4[tid + 256 * j];
    }
    __syncthreads();

    if (wave == 0) {
        // Load this batch's adj row into registers (coalesced, wave 0 only).
        float v[16];
#pragma unroll
        for (int j = 0; j < 16; ++j)
            v[j] = adj[b * RR + lane + 64 * j];

        unsigned int sel = 0u;    // bit j: region lane+64j selected
        unsigned int dead = 0u;   // bit j: region lane+64j suppressed/selected
        int nsel = 0;

        for (int it = 0; it < K_ACTIVE; ++it) {
            // per-lane argmax over alive slots (tree; tie keeps lower j)
            float tv[16]; int ti[16];
#pragma unroll
            for (int j = 0; j < 16; ++j) {
                tv[j] = ((dead >> j) & 1u) ? -INFINITY : v[j];
                ti[j] = lane + 64 * j;
            }
#pragma unroll
            for (int s = 8; s >= 1; s >>= 1) {
#pragma unroll
                for (int j = 0; j < 8; ++j) {
                    if (j < s) {
                        if (tv[j + s] > tv[j]) { tv[j] = tv[j + s]; ti[j] = ti[j + s]; }
                    }
                }
            }
            float m = tv[0];
            int mi = ti[0];

            // wave-64 butterfly argmax (tie -> lowest index)
#pragma unroll
            for (int off = 32; off > 0; off >>= 1) {
                const float ov = __shfl_xor(m, off);
                const int   oi = __shfl_xor(mi, off);
                if (ov > m || (ov == m && oi < mi)) { m = ov; mi = oi; }
            }
            // all lanes agree on (m, mi) now

            if (m == -INFINITY) break;   // parity with reference exhaustion

            if (lane == 0) sel_r[nsel] = mi;
            nsel++;

            // suppress mi and its 6 neighbors (bitmask updates)
            int sup[7];
            sup[0] = mi;
            const int base = mi * 6;
#pragma unroll
            for (int k = 0; k < 6; ++k) sup[k + 1] = nb_lds[base + k];  // broadcast

            sel |= ((mi & 63) == lane) ? (1u << (mi >> 6)) : 0u;
#pragma unroll
            for (int k = 0; k < 7; ++k)
                dead |= ((sup[k] & 63) == lane) ? (1u << (sup[k] >> 6)) : 0u;
        }

        if (lane == 0) nsel_lds = nsel;

        // hard output for this batch
#pragma unroll
        for (int j = 0; j < 16; ++j)
            hard[b * RR + lane + 64 * j] = ((sel >> j) & 1u) ? 1.0f : 0.0f;
    }
    __syncthreads();

    // All 4 waves: copy selected rows H[r,b,:] -> Hs[r,b,:] (4 KB each).
    const int nsel = nsel_lds;
    for (int s = wave; s < nsel; s += 4) {
        const int r = sel_r[s];
        const size_t off = ((size_t)r * BB + b) * DD;
        const float4* src = (const float4*)(H + off);
        float4* dst = (float4*)(Hs + off);
        float4 t0 = src[lane];
        float4 t1 = src[lane + 64];
        float4 t2 = src[lane + 128];
        float4 t3 = src[lane + 192];
        dst[lane]       = t0;
        dst[lane + 64]  = t1;
        dst[lane + 128] = t2;
        dst[lane + 192] = t3;
    }
}

extern "C" void kernel_launch(void* const* d_in, const int* in_sizes, int n_in,
                              void* d_out, int out_size, void* d_ws, size_t ws_size,
                              hipStream_t stream) {
    const float* H     = (const float*)d_in[0];   // [R,B,D]
    const float* msg   = (const float*)d_in[1];   // [R,B,D]
    const float* w     = (const float*)d_in[2];   // [D]
    const float* theta = (const float*)d_in[3];   // [R]
    const float* refr  = (const float*)d_in[4];   // [B,R]
    const float* fb    = (const float*)d_in[5];   // [B,R]
    const int*   nbrs  = (const int*)d_in[6];     // [R,6]

    float* out  = (float*)d_out;
    float* Hs   = out;                                   // [R,B,D]
    float* hard = out + (size_t)RR * BB * DD;            // [B,R]
    float* adj  = hard + (size_t)BB * RR;                // [B,R]

    score_kernel<<<RR * BB / 4, 256, 0, stream>>>(H, msg, w, theta, refr, fb, adj, Hs);
    nms_gate_kernel<<<BB, 256, 0, stream>>>(adj, nbrs, H, hard, Hs);
}